// Round 15
// baseline (142.007 us; speedup 1.0000x reference)
//
#include <hip/hip_runtime.h>
#include <hip/hip_bf16.h>
#include <stdint.h>

typedef unsigned short u16;
typedef unsigned int u32;
typedef __attribute__((ext_vector_type(8))) short bf16x8;
typedef __attribute__((ext_vector_type(4))) float f32x4;
typedef __attribute__((ext_vector_type(16))) float f32x16;
typedef __attribute__((ext_vector_type(4))) u32 u32x4;

#define SEQ    4096
#define EMB    512
#define HEADS  8
#define HDIM   64
#define NBATCH 2
#define WSZ    (EMB * EMB)

__device__ __forceinline__ u16 f2bf(float f) {
  unsigned u = __builtin_bit_cast(unsigned, f);
  u += 0x7fffu + ((u >> 16) & 1u);
  return (u16)(u >> 16);
}
__device__ __forceinline__ float bf2f(u16 x) {
  return __builtin_bit_cast(float, (u32)x << 16);
}

__device__ __forceinline__ void gld_lds16(const void* g, void* lds) {
  __builtin_amdgcn_global_load_lds(
      (const __attribute__((address_space(1))) unsigned int*)(uintptr_t)g,
      (__attribute__((address_space(3))) unsigned int*)(uint32_t)(uintptr_t)lds,
      16, 0, 0);
}

#define CVT_PK(lo, hi) ({ u32 _r; \
  asm("v_cvt_pk_bf16_f32 %0, %1, %2" : "=v"(_r) : "v"(lo), "v"(hi)); _r; })

// bare HW exp2 (1 instr; exp2f without fast-math goes through OCML polyfill)
#define EXP2(x) ({ float _r; asm("v_exp_f32 %0, %1" : "=v"(_r) : "v"(x)); _r; })

// ---- shared 128x128 GEMM mainloop: C = A[m0:,512] * B[n0:,512]^T ----
template <bool ABF16, bool BBF16>
__device__ __forceinline__ void gemm512_tile(const void* __restrict__ Av,
                                             const void* __restrict__ Bv,
                                             u16* lA, u16* lB,
                                             int m0, int n0,
                                             f32x4 acc[4][4]) {
  const int tid  = threadIdx.x;
  const int lane = tid & 63;
  const int wid  = tid >> 6;
  const int wr   = wid >> 1, wc = wid & 1;
  const int srow = lane >> 2;
  const int soff = (lane & 3) * 8;

  for (int k0 = 0; k0 < EMB; k0 += 32) {
    __syncthreads();
    if constexpr (ABF16) {
      const u16* X = (const u16*)Av;
#pragma unroll
      for (int i = 0; i < 2; ++i) {
        int rbase = wid * 32 + i * 16;
        gld_lds16(X + (size_t)(m0 + rbase + srow) * EMB + k0 + soff, lA + rbase * 32);
      }
    } else {
      const float* X = (const float*)Av;
#pragma unroll
      for (int i = 0; i < 4; ++i) {
        int chunk = i * 256 + tid;
        int row = chunk >> 3;
        int c4  = (chunk & 7) * 4;
        float4 v = *(const float4*)(X + (size_t)(m0 + row) * EMB + k0 + c4);
        ushort4 b;
        b.x = f2bf(v.x); b.y = f2bf(v.y); b.z = f2bf(v.z); b.w = f2bf(v.w);
        *(ushort4*)(lA + row * 32 + c4) = b;
      }
    }
    if constexpr (BBF16) {
      const u16* W = (const u16*)Bv;
#pragma unroll
      for (int i = 0; i < 2; ++i) {
        int rbase = wid * 32 + i * 16;
        gld_lds16(W + (size_t)(n0 + rbase + srow) * EMB + k0 + soff, lB + rbase * 32);
      }
    } else {
      const float* W = (const float*)Bv;
#pragma unroll
      for (int i = 0; i < 4; ++i) {
        int chunk = i * 256 + tid;
        int row = chunk >> 3;
        int c4  = (chunk & 7) * 4;
        float4 v = *(const float4*)(W + (size_t)(n0 + row) * EMB + k0 + c4);
        ushort4 b;
        b.x = f2bf(v.x); b.y = f2bf(v.y); b.z = f2bf(v.z); b.w = f2bf(v.w);
        *(ushort4*)(lB + row * 32 + c4) = b;
      }
    }
    __syncthreads();

    bf16x8 a[4], b[4];
#pragma unroll
    for (int t = 0; t < 4; ++t) {
      a[t] = *(const bf16x8*)(lA + (wr * 64 + t * 16 + (lane & 15)) * 32 + (lane >> 4) * 8);
      b[t] = *(const bf16x8*)(lB + (wc * 64 + t * 16 + (lane & 15)) * 32 + (lane >> 4) * 8);
    }
#pragma unroll
    for (int mr = 0; mr < 4; ++mr)
#pragma unroll
      for (int nc = 0; nc < 4; ++nc)
        acc[mr][nc] = __builtin_amdgcn_mfma_f32_16x16x32_bf16(a[mr], b[nc], acc[mr][nc], 0, 0, 0);
  }
}

// ---- convert W_Q, W_K, W_V (f32) -> bf16 in ws ----
__global__ __launch_bounds__(256) void k_wconv(
    const float* __restrict__ wq, const float* __restrict__ wk,
    const float* __restrict__ wv, u16* __restrict__ wall) {
  const int t = blockIdx.x * 256 + threadIdx.x;
  const int w = t >> 15, off = (t & 32767) * 8;
  const float* src = (w == 0) ? wq : (w == 1) ? wk : wv;
  u16* dst = wall + (size_t)w * WSZ + off;
#pragma unroll
  for (int i = 0; i < 2; ++i) {
    float4 v = *(const float4*)(src + off + i * 4);
    ushort4 b;
    b.x = f2bf(v.x); b.y = f2bf(v.y); b.z = f2bf(v.z); b.w = f2bf(v.w);
    *(ushort4*)(dst + i * 4) = b;
  }
}

// ---- QKV projections: grid (64, 4, 3).
// z=0 (Q): scatter [n][h][s][d], pre-scaled by log2(e)/sqrt(512).
// z=1 (K): scatter [n][h][s][d].
// z=2 (V): V^T (A = W_V bf16, B = x_v f32) -> [n][h][d][s], coalesced.
__global__ __launch_bounds__(256, 2) void k_proj_qkv(
    const float* __restrict__ xq, const float* __restrict__ xk, const float* __restrict__ xv,
    const u16* __restrict__ wall,
    u16* __restrict__ yq, u16* __restrict__ yk, u16* __restrict__ yv) {
  __shared__ u16 lA[128 * 32];
  __shared__ u16 lB[128 * 32];
  const int z = blockIdx.z;
  const int lane = threadIdx.x & 63, wid = threadIdx.x >> 6;
  const int wr = wid >> 1, wc = wid & 1;

  if (z == 2) {
    const int m0 = blockIdx.y * 128, n0 = blockIdx.x * 128;
    f32x4 acc[4][4] = {};
    gemm512_tile<true, false>(wall + 2 * WSZ, xv, lA, lB, m0, n0, acc);
#pragma unroll
    for (int mr = 0; mr < 4; ++mr)
#pragma unroll
      for (int nc = 0; nc < 4; ++nc)
#pragma unroll
        for (int j = 0; j < 4; ++j) {
          int m = m0 + wr * 64 + mr * 16 + (lane >> 4) * 4 + j;  // h*64+d
          int c = n0 + wc * 64 + nc * 16 + (lane & 15);          // n*4096+s
          int hh = m >> 6, d = m & 63;
          int n = c >> 12, s = c & (SEQ - 1);
          yv[(((size_t)(n * HEADS + hh)) * HDIM + d) * SEQ + s] = f2bf(acc[mr][nc][j]);
        }
    return;
  }

  const float* X = (z == 0) ? xq : xk;
  const u16* W   = wall + (size_t)z * WSZ;
  u16* Y         = (z == 0) ? yq : yk;
  const float oscale = (z == 0) ? 0.06375873f : 1.0f;  // log2(e)/sqrt(512) into Q
  const int m0 = blockIdx.x * 128, n0 = blockIdx.y * 128;
  f32x4 acc[4][4] = {};
  gemm512_tile<false, true>(X, W, lA, lB, m0, n0, acc);
#pragma unroll
  for (int mr = 0; mr < 4; ++mr)
#pragma unroll
    for (int nc = 0; nc < 4; ++nc)
#pragma unroll
      for (int j = 0; j < 4; ++j) {
        int m = m0 + wr * 64 + mr * 16 + (lane >> 4) * 4 + j;
        int c = n0 + wc * 64 + nc * 16 + (lane & 15);
        int n = m >> 12, s = m & (SEQ - 1);
        int hh = c >> 6, d = c & 63;
        Y[(((size_t)(n * HEADS + hh)) * SEQ + s) * HDIM + d] = f2bf(acc[mr][nc][j] * oscale);
      }
}

// ---- output projection: grid (64, 4), A bf16 (aws), B = wfc f32, out f32 ----
__global__ __launch_bounds__(256, 2) void k_proj_out(
    const u16* __restrict__ X, const float* __restrict__ W, float* __restrict__ Y) {
  __shared__ u16 lA[128 * 32];
  __shared__ u16 lB[128 * 32];
  const int m0 = blockIdx.x * 128, n0 = blockIdx.y * 128;
  f32x4 acc[4][4] = {};
  gemm512_tile<true, false>(X, W, lA, lB, m0, n0, acc);

  const int lane = threadIdx.x & 63, wid = threadIdx.x >> 6;
  const int wr = wid >> 1, wc = wid & 1;
#pragma unroll
  for (int mr = 0; mr < 4; ++mr)
#pragma unroll
    for (int nc = 0; nc < 4; ++nc)
#pragma unroll
      for (int j = 0; j < 4; ++j) {
        int m = m0 + wr * 64 + mr * 16 + (lane >> 4) * 4 + j;
        int c = n0 + wc * 64 + nc * 16 + (lane & 15);
        Y[(size_t)m * EMB + c] = acc[mr][nc][j];
      }
}

// ---- flash attention, swapped-operand 32x32, zero-reference softmax ----
// S = KV-split factor. S>1: writes bf16 unnormalized partial O + f32 l
// (same zero reference for all splits -> merge is pure sums, no exp).
// lsum via ones-MFMA (HW-verified correct; elementwise variant regressed
// numerics for reasons not yet explained -- do not re-attempt without a
// bit-level explanation).
template <int S>
__global__ __launch_bounds__(256, 2) void k_attn(
    const u16* __restrict__ Qg, const u16* __restrict__ Kg,
    const u16* __restrict__ Vt, u16* __restrict__ Og,
    u16* __restrict__ pOb, float* __restrict__ pL) {
  __shared__ u16 lK[2][64 * 64];   // [kv-sigma][d], chunk ^ (row&7)
  __shared__ u16 lV[2][64 * 64];   // [d][kv], chunk ^ (d&7)
  constexpr int LS = (S == 4) ? 2 : (S == 2) ? 1 : 0;

  // bijective XCD swizzle: all blocks of one nh land on one XCD (L2 reuse)
  int flat = blockIdx.x + 32 * blockIdx.y + 512 * blockIdx.z;
  int xcd = flat & 7, i = flat >> 3;
  int bx = i & 31;
  int bz = (S > 1) ? ((i >> 5) & (S - 1)) : 0;
  int nh = xcd + 8 * (i >> (5 + LS));

  const int tid = threadIdx.x, lane = tid & 63, wid = tid >> 6;
  const int l31 = lane & 31, h = lane >> 5;
  const int q0 = bx * 128 + wid * 32;
  const int kvb = bz * (SEQ / S);
  const int NT  = SEQ / S / 64;

  const u16* Qh = Qg + (size_t)nh * SEQ * HDIM;
  const u16* Kh = Kg + (size_t)nh * SEQ * HDIM;
  const u16* Vh = Vt + (size_t)nh * HDIM * SEQ;   // V^T: [d][s]

  bf16x8 qf[4];
#pragma unroll
  for (int t = 0; t < 4; ++t)
    qf[t] = *(const bf16x8*)&Qh[(size_t)(q0 + l31) * HDIM + t * 16 + h * 8];

  const u32x4 ones4 = {0x3F803F80u, 0x3F803F80u, 0x3F803F80u, 0x3F803F80u};
  const bf16x8 onesf = __builtin_bit_cast(bf16x8, ones4);

  f32x16 o0 = {}, o1 = {};    // O^T tiles: d 0-31 / 32-63 (rows), q = l31
  f32x16 lacc = {};           // column-sum accumulator (lsum)

  auto stage = [&](int buf, int kv0) {
#pragma unroll
    for (int i2 = 0; i2 < 2; ++i2) {
      int g = i2 * 256 + tid;
      int kr = g >> 3, kc = g & 7;
      int krp = (kr & 0x33) | ((kr & 4) << 1) | ((kr & 8) >> 1);  // swap bits 2,3
      gld_lds16(Kh + (size_t)(kv0 + krp) * HDIM + ((kc ^ (kr & 7)) * 8),
                &lK[buf][g * 8]);
    }
#pragma unroll
    for (int i2 = 0; i2 < 2; ++i2) {
      int g = i2 * 256 + tid;
      int vd = g >> 3, vc = g & 7;
      gld_lds16(Vh + (size_t)vd * SEQ + kv0 + ((vc ^ (vd & 7)) * 8),
                &lV[buf][g * 8]);
    }
  };

  stage(0, kvb);
  asm volatile("s_waitcnt vmcnt(0)" ::: "memory");
  __syncthreads();

  for (int t = 0; t < NT; ++t) {
    const int cur = t & 1, nxt = cur ^ 1;
    if (t < NT - 1) stage(nxt, kvb + (t + 1) * 64);

    // ---- QK^T (swapped): S^T = K * Q^T ----
    f32x16 sA = {}, sB = {};
    __builtin_amdgcn_s_setprio(1);
#pragma unroll
    for (int tt = 0; tt < 4; ++tt) {
      int co = (tt * 16 + h * 8) ^ ((l31 & 7) << 3);
      bf16x8 k0 = *(const bf16x8*)&lK[cur][l31 * 64 + co];
      bf16x8 k1 = *(const bf16x8*)&lK[cur][(32 + l31) * 64 + co];
      sA = __builtin_amdgcn_mfma_f32_32x32x16_bf16(k0, qf[tt], sA, 0, 0, 0);
      sB = __builtin_amdgcn_mfma_f32_32x32x16_bf16(k1, qf[tt], sB, 0, 0, 0);
    }
    __builtin_amdgcn_s_setprio(0);

    // ---- p = 2^S, bare v_exp_f32 (zero reference; Q pre-scaled by log2e) ----
#pragma unroll
    for (int r = 0; r < 16; ++r) {
      sA[r] = EXP2(sA[r]);
      sB[r] = EXP2(sB[r]);
    }

    // ---- pack P -> PV B-frags, pure in-lane (sigma K-permute) ----
    u32x4 pfr[4];
#pragma unroll
    for (int w = 0; w < 4; ++w) {
      pfr[0][w] = CVT_PK(sA[2 * w],     sA[2 * w + 1]);
      pfr[1][w] = CVT_PK(sA[8 + 2 * w], sA[8 + 2 * w + 1]);
      pfr[2][w] = CVT_PK(sB[2 * w],     sB[2 * w + 1]);
      pfr[3][w] = CVT_PK(sB[8 + 2 * w], sB[8 + 2 * w + 1]);
    }

    // ---- lsum on MFMA pipe ----
#pragma unroll
    for (int tt = 0; tt < 4; ++tt)
      lacc = __builtin_amdgcn_mfma_f32_32x32x16_bf16(
          onesf, __builtin_bit_cast(bf16x8, pfr[tt]), lacc, 0, 0, 0);

    // ---- PV: O^T = V^T * P^T ----
#pragma unroll
    for (int dt = 0; dt < 2; ++dt) {
      bf16x8 vf[4];
#pragma unroll
      for (int tt = 0; tt < 4; ++tt) {
        int d = dt * 32 + l31;
        vf[tt] = *(const bf16x8*)&lV[cur][d * 64 + (((tt * 2 + h) ^ (d & 7)) * 8)];
      }
      __builtin_amdgcn_s_setprio(1);
#pragma unroll
      for (int tt = 0; tt < 4; ++tt) {
        bf16x8 pb = __builtin_bit_cast(bf16x8, pfr[tt]);
        if (dt == 0) o0 = __builtin_amdgcn_mfma_f32_32x32x16_bf16(vf[tt], pb, o0, 0, 0, 0);
        else         o1 = __builtin_amdgcn_mfma_f32_32x32x16_bf16(vf[tt], pb, o1, 0, 0, 0);
      }
      __builtin_amdgcn_s_setprio(0);
    }

    asm volatile("s_waitcnt vmcnt(0)" ::: "memory");
    __syncthreads();
  }

  const int q = q0 + l31;
  if constexpr (S == 1) {
    const float linv = 1.f / lacc[0];
    const int n = nh >> 3, hh = nh & 7;
#pragma unroll
    for (int r = 0; r < 16; ++r) {
      int row = (r & 3) + 8 * (r >> 2) + 4 * h;
      Og[((size_t)(n * SEQ + q)) * EMB + hh * 64 + row] = f2bf(o0[r] * linv);
      Og[((size_t)(n * SEQ + q)) * EMB + hh * 64 + 32 + row] = f2bf(o1[r] * linv);
    }
  } else {
    // bf16 unnormalized partial O + f32 l (shared zero reference)
    const size_t PO_E = (size_t)16 * SEQ * HDIM;
    u16* po = pOb + (size_t)bz * PO_E + ((size_t)nh * SEQ + q) * HDIM;
#pragma unroll
    for (int g = 0; g < 4; ++g) {
      ushort4 a = {f2bf(o0[4 * g + 0]), f2bf(o0[4 * g + 1]),
                   f2bf(o0[4 * g + 2]), f2bf(o0[4 * g + 3])};
      ushort4 b = {f2bf(o1[4 * g + 0]), f2bf(o1[4 * g + 1]),
                   f2bf(o1[4 * g + 2]), f2bf(o1[4 * g + 3])};
      *(ushort4*)(po + 8 * g + 4 * h) = a;
      *(ushort4*)(po + 32 + 8 * g + 4 * h) = b;
    }
    if (h == 0)
      pL[(size_t)bz * 16 * SEQ + (size_t)nh * SEQ + q] = lacc[0];
  }
}

// ---- merge S partials (pure sums, no exp) -> bf16 aws [n][s][h*64+d] ----
template <int S>
__global__ __launch_bounds__(256) void k_merge(const u16* __restrict__ pOb,
                                               const float* __restrict__ pL,
                                               u16* __restrict__ aws) {
  const int idx = blockIdx.x * 256 + threadIdx.x;   // 0..524287
  const int row = idx >> 3;
  const int ch  = idx & 7;
  float l = 0.f;
#pragma unroll
  for (int s = 0; s < S; ++s) l += pL[(size_t)s * 16 * SEQ + row];
  const float inv = 1.f / l;
  float acc[8] = {};
  const size_t PO_E = (size_t)16 * SEQ * HDIM;
#pragma unroll
  for (int s = 0; s < S; ++s) {
    const u16* p = pOb + (size_t)s * PO_E + (size_t)row * HDIM + ch * 8;
    ushort4 a = *(const ushort4*)p;
    ushort4 b = *(const ushort4*)(p + 4);
    acc[0] += bf2f(a.x); acc[1] += bf2f(a.y); acc[2] += bf2f(a.z); acc[3] += bf2f(a.w);
    acc[4] += bf2f(b.x); acc[5] += bf2f(b.y); acc[6] += bf2f(b.z); acc[7] += bf2f(b.w);
  }
  ushort4 r0 = {f2bf(acc[0] * inv), f2bf(acc[1] * inv), f2bf(acc[2] * inv), f2bf(acc[3] * inv)};
  ushort4 r1 = {f2bf(acc[4] * inv), f2bf(acc[5] * inv), f2bf(acc[6] * inv), f2bf(acc[7] * inv)};
  const int nh = row >> 12, q = row & (SEQ - 1);
  const int n = nh >> 3, hh = nh & 7;
  u16* dst = aws + ((size_t)(n * SEQ + q)) * EMB + hh * 64 + ch * 8;
  *(ushort4*)dst = r0;
  *(ushort4*)(dst + 4) = r1;
}

extern "C" void kernel_launch(void* const* d_in, const int* in_sizes, int n_in,
                              void* d_out, int out_size, void* d_ws, size_t ws_size,
                              hipStream_t stream) {
  const float* xv  = (const float*)d_in[0];
  const float* xq  = (const float*)d_in[1];
  const float* xk  = (const float*)d_in[2];
  const float* wq  = (const float*)d_in[3];
  const float* wk  = (const float*)d_in[4];
  const float* wv  = (const float*)d_in[5];
  const float* wfc = (const float*)d_in[6];
  float* out = (float*)d_out;
  u16* ws    = (u16*)d_ws;

  const size_t PSZ  = (size_t)NBATCH * HEADS * SEQ * HDIM;  // 4,194,304 elems
  const size_t PO_E = (size_t)16 * SEQ * HDIM;              // elems per split
  const size_t base = 4 * PSZ * sizeof(u16);                // 33.55 MB
  if (ws_size < base + 3 * WSZ * sizeof(u16)) return;

  u16* qws = ws;
  u16* kws = ws + PSZ;
  u16* vws = ws + 2 * PSZ;     // V^T [n][h][d][s]
  u16* aws = ws + 3 * PSZ;
  u16* scratch = ws + 4 * PSZ; // wall / pOb (disjoint lifetimes)

  const size_t need4 = base + 4 * PO_E * 2 + 4 * (size_t)16 * SEQ * 4;
  const size_t need2 = base + 2 * PO_E * 2 + 2 * (size_t)16 * SEQ * 4;

  k_wconv<<<384, 256, 0, stream>>>(wq, wk, wv, scratch);
  k_proj_qkv<<<dim3(64, 4, 3), 256, 0, stream>>>(xq, xk, xv, scratch, qws, kws, vws);

  if (ws_size >= need4) {
    float* pL = (float*)((char*)d_ws + base + 4 * PO_E * 2);
    k_attn<4><<<dim3(32, 16, 4), 256, 0, stream>>>(qws, kws, vws, aws, scratch, pL);
    k_merge<4><<<2048, 256, 0, stream>>>(scratch, pL, aws);
  } else if (ws_size >= need2) {
    float* pL = (float*)((char*)d_ws + base + 2 * PO_E * 2);
    k_attn<2><<<dim3(32, 16, 2), 256, 0, stream>>>(qws, kws, vws, aws, scratch, pL);
    k_merge<2><<<2048, 256, 0, stream>>>(scratch, pL, aws);
  } else {
    k_attn<1><<<dim3(32, 16, 1), 256, 0, stream>>>(qws, kws, vws, aws, nullptr, nullptr);
  }

  k_proj_out<<<dim3(64, 4), 256, 0, stream>>>(aws, wfc, out);
}

// Round 16
// 141.148 us; speedup vs baseline: 1.0061x; 1.0061x over previous
//
#include <hip/hip_runtime.h>
#include <hip/hip_bf16.h>
#include <stdint.h>

typedef unsigned short u16;
typedef unsigned int u32;
typedef __attribute__((ext_vector_type(8))) short bf16x8;
typedef __attribute__((ext_vector_type(4))) float f32x4;
typedef __attribute__((ext_vector_type(16))) float f32x16;
typedef __attribute__((ext_vector_type(4))) u32 u32x4;

#define SEQ    4096
#define EMB    512
#define HEADS  8
#define HDIM   64
#define NBATCH 2
#define WSZ    (EMB * EMB)

__device__ __forceinline__ u16 f2bf(float f) {
  unsigned u = __builtin_bit_cast(unsigned, f);
  u += 0x7fffu + ((u >> 16) & 1u);
  return (u16)(u >> 16);
}
__device__ __forceinline__ float bf2f(u16 x) {
  return __builtin_bit_cast(float, (u32)x << 16);
}

__device__ __forceinline__ void gld_lds16(const void* g, void* lds) {
  __builtin_amdgcn_global_load_lds(
      (const __attribute__((address_space(1))) unsigned int*)(uintptr_t)g,
      (__attribute__((address_space(3))) unsigned int*)(uint32_t)(uintptr_t)lds,
      16, 0, 0);
}

#define CVT_PK(lo, hi) ({ u32 _r; \
  asm("v_cvt_pk_bf16_f32 %0, %1, %2" : "=v"(_r) : "v"(lo), "v"(hi)); _r; })

// bare HW exp2 (1 instr; exp2f without fast-math goes through OCML polyfill)
#define EXP2(x) ({ float _r; asm("v_exp_f32 %0, %1" : "=v"(_r) : "v"(x)); _r; })

// ---- shared 128x128 GEMM mainloop: C = A[m0:,512] * B[n0:,512]^T ----
template <bool ABF16, bool BBF16>
__device__ __forceinline__ void gemm512_tile(const void* __restrict__ Av,
                                             const void* __restrict__ Bv,
                                             u16* lA, u16* lB,
                                             int m0, int n0,
                                             f32x4 acc[4][4]) {
  const int tid  = threadIdx.x;
  const int lane = tid & 63;
  const int wid  = tid >> 6;
  const int wr   = wid >> 1, wc = wid & 1;
  const int srow = lane >> 2;
  const int soff = (lane & 3) * 8;

  for (int k0 = 0; k0 < EMB; k0 += 32) {
    __syncthreads();
    if constexpr (ABF16) {
      const u16* X = (const u16*)Av;
#pragma unroll
      for (int i = 0; i < 2; ++i) {
        int rbase = wid * 32 + i * 16;
        gld_lds16(X + (size_t)(m0 + rbase + srow) * EMB + k0 + soff, lA + rbase * 32);
      }
    } else {
      const float* X = (const float*)Av;
#pragma unroll
      for (int i = 0; i < 4; ++i) {
        int chunk = i * 256 + tid;
        int row = chunk >> 3;
        int c4  = (chunk & 7) * 4;
        float4 v = *(const float4*)(X + (size_t)(m0 + row) * EMB + k0 + c4);
        ushort4 b;
        b.x = f2bf(v.x); b.y = f2bf(v.y); b.z = f2bf(v.z); b.w = f2bf(v.w);
        *(ushort4*)(lA + row * 32 + c4) = b;
      }
    }
    if constexpr (BBF16) {
      const u16* W = (const u16*)Bv;
#pragma unroll
      for (int i = 0; i < 2; ++i) {
        int rbase = wid * 32 + i * 16;
        gld_lds16(W + (size_t)(n0 + rbase + srow) * EMB + k0 + soff, lB + rbase * 32);
      }
    } else {
      const float* W = (const float*)Bv;
#pragma unroll
      for (int i = 0; i < 4; ++i) {
        int chunk = i * 256 + tid;
        int row = chunk >> 3;
        int c4  = (chunk & 7) * 4;
        float4 v = *(const float4*)(W + (size_t)(n0 + row) * EMB + k0 + c4);
        ushort4 b;
        b.x = f2bf(v.x); b.y = f2bf(v.y); b.z = f2bf(v.z); b.w = f2bf(v.w);
        *(ushort4*)(lB + row * 32 + c4) = b;
      }
    }
    __syncthreads();

    bf16x8 a[4], b[4];
#pragma unroll
    for (int t = 0; t < 4; ++t) {
      a[t] = *(const bf16x8*)(lA + (wr * 64 + t * 16 + (lane & 15)) * 32 + (lane >> 4) * 8);
      b[t] = *(const bf16x8*)(lB + (wc * 64 + t * 16 + (lane & 15)) * 32 + (lane >> 4) * 8);
    }
#pragma unroll
    for (int mr = 0; mr < 4; ++mr)
#pragma unroll
      for (int nc = 0; nc < 4; ++nc)
        acc[mr][nc] = __builtin_amdgcn_mfma_f32_16x16x32_bf16(a[mr], b[nc], acc[mr][nc], 0, 0, 0);
  }
}

// ---- convert W_Q, W_K, W_V (f32) -> bf16 in ws ----
__global__ __launch_bounds__(256) void k_wconv(
    const float* __restrict__ wq, const float* __restrict__ wk,
    const float* __restrict__ wv, u16* __restrict__ wall) {
  const int t = blockIdx.x * 256 + threadIdx.x;
  const int w = t >> 15, off = (t & 32767) * 8;
  const float* src = (w == 0) ? wq : (w == 1) ? wk : wv;
  u16* dst = wall + (size_t)w * WSZ + off;
#pragma unroll
  for (int i = 0; i < 2; ++i) {
    float4 v = *(const float4*)(src + off + i * 4);
    ushort4 b;
    b.x = f2bf(v.x); b.y = f2bf(v.y); b.z = f2bf(v.z); b.w = f2bf(v.w);
    *(ushort4*)(dst + i * 4) = b;
  }
}

// ---- QKV projections: grid (64, 4, 3), XCD-swizzled block decode.
// Pure blockIdx permutation (numerics-invariant): the 4 blocks sharing an
// X row-panel (same x, diff y) and the 8 blocks sharing a W col-tile (same
// y,z, diff g) all get equal flat%8 -> same XCD -> L2-resident reuse.
// z=0 (Q): scatter [n][h][s][d], pre-scaled by log2(e)/sqrt(512).
// z=1 (K): scatter [n][h][s][d].
// z=2 (V): V^T (A = W_V bf16, B = x_v f32) -> [n][h][d][s], coalesced.
__global__ __launch_bounds__(256, 2) void k_proj_qkv(
    const float* __restrict__ xq, const float* __restrict__ xk, const float* __restrict__ xv,
    const u16* __restrict__ wall,
    u16* __restrict__ yq, u16* __restrict__ yk, u16* __restrict__ yv) {
  __shared__ u16 lA[128 * 32];
  __shared__ u16 lB[128 * 32];
  // bijective decode: flat = xcd + 8*by + 32*gx + 256*z
  const int flat = blockIdx.x + 64 * (blockIdx.y + 4 * blockIdx.z);
  const int xcd = flat & 7, j = flat >> 3;
  const int by = j & 3, gx = (j >> 2) & 7, z = j >> 5;
  const int bx = xcd + 8 * gx;

  const int lane = threadIdx.x & 63, wid = threadIdx.x >> 6;
  const int wr = wid >> 1, wc = wid & 1;

  if (z == 2) {
    const int m0 = by * 128, n0 = bx * 128;
    f32x4 acc[4][4] = {};
    gemm512_tile<true, false>(wall + 2 * WSZ, xv, lA, lB, m0, n0, acc);
#pragma unroll
    for (int mr = 0; mr < 4; ++mr)
#pragma unroll
      for (int nc = 0; nc < 4; ++nc)
#pragma unroll
        for (int j2 = 0; j2 < 4; ++j2) {
          int m = m0 + wr * 64 + mr * 16 + (lane >> 4) * 4 + j2;  // h*64+d
          int c = n0 + wc * 64 + nc * 16 + (lane & 15);           // n*4096+s
          int hh = m >> 6, d = m & 63;
          int n = c >> 12, s = c & (SEQ - 1);
          yv[(((size_t)(n * HEADS + hh)) * HDIM + d) * SEQ + s] = f2bf(acc[mr][nc][j2]);
        }
    return;
  }

  const float* X = (z == 0) ? xq : xk;
  const u16* W   = wall + (size_t)z * WSZ;
  u16* Y         = (z == 0) ? yq : yk;
  const float oscale = (z == 0) ? 0.06375873f : 1.0f;  // log2(e)/sqrt(512) into Q
  const int m0 = bx * 128, n0 = by * 128;
  f32x4 acc[4][4] = {};
  gemm512_tile<false, true>(X, W, lA, lB, m0, n0, acc);
#pragma unroll
  for (int mr = 0; mr < 4; ++mr)
#pragma unroll
    for (int nc = 0; nc < 4; ++nc)
#pragma unroll
      for (int j2 = 0; j2 < 4; ++j2) {
        int m = m0 + wr * 64 + mr * 16 + (lane >> 4) * 4 + j2;
        int c = n0 + wc * 64 + nc * 16 + (lane & 15);
        int n = m >> 12, s = m & (SEQ - 1);
        int hh = c >> 6, d = c & 63;
        Y[(((size_t)(n * HEADS + hh)) * SEQ + s) * HDIM + d] = f2bf(acc[mr][nc][j2] * oscale);
      }
}

// ---- output projection: grid (64, 4), XCD-swizzled decode (same scheme) ----
__global__ __launch_bounds__(256, 2) void k_proj_out(
    const u16* __restrict__ X, const float* __restrict__ W, float* __restrict__ Y) {
  __shared__ u16 lA[128 * 32];
  __shared__ u16 lB[128 * 32];
  const int flat = blockIdx.x + 64 * blockIdx.y;
  const int xcd = flat & 7, j = flat >> 3;
  const int by = j & 3, gx = j >> 2;
  const int bx = xcd + 8 * gx;
  const int m0 = bx * 128, n0 = by * 128;
  f32x4 acc[4][4] = {};
  gemm512_tile<true, false>(X, W, lA, lB, m0, n0, acc);

  const int lane = threadIdx.x & 63, wid = threadIdx.x >> 6;
  const int wr = wid >> 1, wc = wid & 1;
#pragma unroll
  for (int mr = 0; mr < 4; ++mr)
#pragma unroll
    for (int nc = 0; nc < 4; ++nc)
#pragma unroll
      for (int j2 = 0; j2 < 4; ++j2) {
        int m = m0 + wr * 64 + mr * 16 + (lane >> 4) * 4 + j2;
        int c = n0 + wc * 64 + nc * 16 + (lane & 15);
        Y[(size_t)m * EMB + c] = acc[mr][nc][j2];
      }
}

// ---- flash attention, swapped-operand 32x32, zero-reference softmax ----
// S = KV-split factor. S>1: writes bf16 unnormalized partial O + f32 l
// (same zero reference for all splits -> merge is pure sums, no exp).
// lsum via ones-MFMA (HW-verified correct; elementwise variant regressed
// numerics for reasons not yet explained -- do not re-attempt without a
// bit-level explanation).
template <int S>
__global__ __launch_bounds__(256, 2) void k_attn(
    const u16* __restrict__ Qg, const u16* __restrict__ Kg,
    const u16* __restrict__ Vt, u16* __restrict__ Og,
    u16* __restrict__ pOb, float* __restrict__ pL) {
  __shared__ u16 lK[2][64 * 64];   // [kv-sigma][d], chunk ^ (row&7)
  __shared__ u16 lV[2][64 * 64];   // [d][kv], chunk ^ (d&7)
  constexpr int LS = (S == 4) ? 2 : (S == 2) ? 1 : 0;

  // bijective XCD swizzle: all blocks of one nh land on one XCD (L2 reuse)
  int flat = blockIdx.x + 32 * blockIdx.y + 512 * blockIdx.z;
  int xcd = flat & 7, i = flat >> 3;
  int bx = i & 31;
  int bz = (S > 1) ? ((i >> 5) & (S - 1)) : 0;
  int nh = xcd + 8 * (i >> (5 + LS));

  const int tid = threadIdx.x, lane = tid & 63, wid = tid >> 6;
  const int l31 = lane & 31, h = lane >> 5;
  const int q0 = bx * 128 + wid * 32;
  const int kvb = bz * (SEQ / S);
  const int NT  = SEQ / S / 64;

  const u16* Qh = Qg + (size_t)nh * SEQ * HDIM;
  const u16* Kh = Kg + (size_t)nh * SEQ * HDIM;
  const u16* Vh = Vt + (size_t)nh * HDIM * SEQ;   // V^T: [d][s]

  bf16x8 qf[4];
#pragma unroll
  for (int t = 0; t < 4; ++t)
    qf[t] = *(const bf16x8*)&Qh[(size_t)(q0 + l31) * HDIM + t * 16 + h * 8];

  const u32x4 ones4 = {0x3F803F80u, 0x3F803F80u, 0x3F803F80u, 0x3F803F80u};
  const bf16x8 onesf = __builtin_bit_cast(bf16x8, ones4);

  f32x16 o0 = {}, o1 = {};    // O^T tiles: d 0-31 / 32-63 (rows), q = l31
  f32x16 lacc = {};           // column-sum accumulator (lsum)

  auto stage = [&](int buf, int kv0) {
#pragma unroll
    for (int i2 = 0; i2 < 2; ++i2) {
      int g = i2 * 256 + tid;
      int kr = g >> 3, kc = g & 7;
      int krp = (kr & 0x33) | ((kr & 4) << 1) | ((kr & 8) >> 1);  // swap bits 2,3
      gld_lds16(Kh + (size_t)(kv0 + krp) * HDIM + ((kc ^ (kr & 7)) * 8),
                &lK[buf][g * 8]);
    }
#pragma unroll
    for (int i2 = 0; i2 < 2; ++i2) {
      int g = i2 * 256 + tid;
      int vd = g >> 3, vc = g & 7;
      gld_lds16(Vh + (size_t)vd * SEQ + kv0 + ((vc ^ (vd & 7)) * 8),
                &lV[buf][g * 8]);
    }
  };

  stage(0, kvb);
  asm volatile("s_waitcnt vmcnt(0)" ::: "memory");
  __syncthreads();

  for (int t = 0; t < NT; ++t) {
    const int cur = t & 1, nxt = cur ^ 1;
    if (t < NT - 1) stage(nxt, kvb + (t + 1) * 64);

    // ---- QK^T (swapped): S^T = K * Q^T ----
    f32x16 sA = {}, sB = {};
    __builtin_amdgcn_s_setprio(1);
#pragma unroll
    for (int tt = 0; tt < 4; ++tt) {
      int co = (tt * 16 + h * 8) ^ ((l31 & 7) << 3);
      bf16x8 k0 = *(const bf16x8*)&lK[cur][l31 * 64 + co];
      bf16x8 k1 = *(const bf16x8*)&lK[cur][(32 + l31) * 64 + co];
      sA = __builtin_amdgcn_mfma_f32_32x32x16_bf16(k0, qf[tt], sA, 0, 0, 0);
      sB = __builtin_amdgcn_mfma_f32_32x32x16_bf16(k1, qf[tt], sB, 0, 0, 0);
    }
    __builtin_amdgcn_s_setprio(0);

    // ---- p = 2^S, bare v_exp_f32 (zero reference; Q pre-scaled by log2e) ----
#pragma unroll
    for (int r = 0; r < 16; ++r) {
      sA[r] = EXP2(sA[r]);
      sB[r] = EXP2(sB[r]);
    }

    // ---- pack P -> PV B-frags, pure in-lane (sigma K-permute) ----
    u32x4 pfr[4];
#pragma unroll
    for (int w = 0; w < 4; ++w) {
      pfr[0][w] = CVT_PK(sA[2 * w],     sA[2 * w + 1]);
      pfr[1][w] = CVT_PK(sA[8 + 2 * w], sA[8 + 2 * w + 1]);
      pfr[2][w] = CVT_PK(sB[2 * w],     sB[2 * w + 1]);
      pfr[3][w] = CVT_PK(sB[8 + 2 * w], sB[8 + 2 * w + 1]);
    }

    // ---- lsum on MFMA pipe ----
#pragma unroll
    for (int tt = 0; tt < 4; ++tt)
      lacc = __builtin_amdgcn_mfma_f32_32x32x16_bf16(
          onesf, __builtin_bit_cast(bf16x8, pfr[tt]), lacc, 0, 0, 0);

    // ---- PV: O^T = V^T * P^T ----
#pragma unroll
    for (int dt = 0; dt < 2; ++dt) {
      bf16x8 vf[4];
#pragma unroll
      for (int tt = 0; tt < 4; ++tt) {
        int d = dt * 32 + l31;
        vf[tt] = *(const bf16x8*)&lV[cur][d * 64 + (((tt * 2 + h) ^ (d & 7)) * 8)];
      }
      __builtin_amdgcn_s_setprio(1);
#pragma unroll
      for (int tt = 0; tt < 4; ++tt) {
        bf16x8 pb = __builtin_bit_cast(bf16x8, pfr[tt]);
        if (dt == 0) o0 = __builtin_amdgcn_mfma_f32_32x32x16_bf16(vf[tt], pb, o0, 0, 0, 0);
        else         o1 = __builtin_amdgcn_mfma_f32_32x32x16_bf16(vf[tt], pb, o1, 0, 0, 0);
      }
      __builtin_amdgcn_s_setprio(0);
    }

    asm volatile("s_waitcnt vmcnt(0)" ::: "memory");
    __syncthreads();
  }

  const int q = q0 + l31;
  if constexpr (S == 1) {
    const float linv = 1.f / lacc[0];
    const int n = nh >> 3, hh = nh & 7;
#pragma unroll
    for (int r = 0; r < 16; ++r) {
      int row = (r & 3) + 8 * (r >> 2) + 4 * h;
      Og[((size_t)(n * SEQ + q)) * EMB + hh * 64 + row] = f2bf(o0[r] * linv);
      Og[((size_t)(n * SEQ + q)) * EMB + hh * 64 + 32 + row] = f2bf(o1[r] * linv);
    }
  } else {
    // bf16 unnormalized partial O + f32 l (shared zero reference)
    const size_t PO_E = (size_t)16 * SEQ * HDIM;
    u16* po = pOb + (size_t)bz * PO_E + ((size_t)nh * SEQ + q) * HDIM;
#pragma unroll
    for (int g = 0; g < 4; ++g) {
      ushort4 a = {f2bf(o0[4 * g + 0]), f2bf(o0[4 * g + 1]),
                   f2bf(o0[4 * g + 2]), f2bf(o0[4 * g + 3])};
      ushort4 b = {f2bf(o1[4 * g + 0]), f2bf(o1[4 * g + 1]),
                   f2bf(o1[4 * g + 2]), f2bf(o1[4 * g + 3])};
      *(ushort4*)(po + 8 * g + 4 * h) = a;
      *(ushort4*)(po + 32 + 8 * g + 4 * h) = b;
    }
    if (h == 0)
      pL[(size_t)bz * 16 * SEQ + (size_t)nh * SEQ + q] = lacc[0];
  }
}

// ---- merge S partials (pure sums, no exp) -> bf16 aws [n][s][h*64+d] ----
template <int S>
__global__ __launch_bounds__(256) void k_merge(const u16* __restrict__ pOb,
                                               const float* __restrict__ pL,
                                               u16* __restrict__ aws) {
  const int idx = blockIdx.x * 256 + threadIdx.x;   // 0..524287
  const int row = idx >> 3;
  const int ch  = idx & 7;
  float l = 0.f;
#pragma unroll
  for (int s = 0; s < S; ++s) l += pL[(size_t)s * 16 * SEQ + row];
  const float inv = 1.f / l;
  float acc[8] = {};
  const size_t PO_E = (size_t)16 * SEQ * HDIM;
#pragma unroll
  for (int s = 0; s < S; ++s) {
    const u16* p = pOb + (size_t)s * PO_E + (size_t)row * HDIM + ch * 8;
    ushort4 a = *(const ushort4*)p;
    ushort4 b = *(const ushort4*)(p + 4);
    acc[0] += bf2f(a.x); acc[1] += bf2f(a.y); acc[2] += bf2f(a.z); acc[3] += bf2f(a.w);
    acc[4] += bf2f(b.x); acc[5] += bf2f(b.y); acc[6] += bf2f(b.z); acc[7] += bf2f(b.w);
  }
  ushort4 r0 = {f2bf(acc[0] * inv), f2bf(acc[1] * inv), f2bf(acc[2] * inv), f2bf(acc[3] * inv)};
  ushort4 r1 = {f2bf(acc[4] * inv), f2bf(acc[5] * inv), f2bf(acc[6] * inv), f2bf(acc[7] * inv)};
  const int nh = row >> 12, q = row & (SEQ - 1);
  const int n = nh >> 3, hh = nh & 7;
  u16* dst = aws + ((size_t)(n * SEQ + q)) * EMB + hh * 64 + ch * 8;
  *(ushort4*)dst = r0;
  *(ushort4*)(dst + 4) = r1;
}

extern "C" void kernel_launch(void* const* d_in, const int* in_sizes, int n_in,
                              void* d_out, int out_size, void* d_ws, size_t ws_size,
                              hipStream_t stream) {
  const float* xv  = (const float*)d_in[0];
  const float* xq  = (const float*)d_in[1];
  const float* xk  = (const float*)d_in[2];
  const float* wq  = (const float*)d_in[3];
  const float* wk  = (const float*)d_in[4];
  const float* wv  = (const float*)d_in[5];
  const float* wfc = (const float*)d_in[6];
  float* out = (float*)d_out;
  u16* ws    = (u16*)d_ws;

  const size_t PSZ  = (size_t)NBATCH * HEADS * SEQ * HDIM;  // 4,194,304 elems
  const size_t PO_E = (size_t)16 * SEQ * HDIM;              // elems per split
  const size_t base = 4 * PSZ * sizeof(u16);                // 33.55 MB
  if (ws_size < base + 3 * WSZ * sizeof(u16)) return;

  u16* qws = ws;
  u16* kws = ws + PSZ;
  u16* vws = ws + 2 * PSZ;     // V^T [n][h][d][s]
  u16* aws = ws + 3 * PSZ;
  u16* scratch = ws + 4 * PSZ; // wall / pOb (disjoint lifetimes)

  const size_t need4 = base + 4 * PO_E * 2 + 4 * (size_t)16 * SEQ * 4;
  const size_t need2 = base + 2 * PO_E * 2 + 2 * (size_t)16 * SEQ * 4;

  k_wconv<<<384, 256, 0, stream>>>(wq, wk, wv, scratch);
  k_proj_qkv<<<dim3(64, 4, 3), 256, 0, stream>>>(xq, xk, xv, scratch, qws, kws, vws);

  if (ws_size >= need4) {
    float* pL = (float*)((char*)d_ws + base + 4 * PO_E * 2);
    k_attn<4><<<dim3(32, 16, 4), 256, 0, stream>>>(qws, kws, vws, aws, scratch, pL);
    k_merge<4><<<2048, 256, 0, stream>>>(scratch, pL, aws);
  } else if (ws_size >= need2) {
    float* pL = (float*)((char*)d_ws + base + 2 * PO_E * 2);
    k_attn<2><<<dim3(32, 16, 2), 256, 0, stream>>>(qws, kws, vws, aws, scratch, pL);
    k_merge<2><<<2048, 256, 0, stream>>>(scratch, pL, aws);
  } else {
    k_attn<1><<<dim3(32, 16, 1), 256, 0, stream>>>(qws, kws, vws, aws, nullptr, nullptr);
  }

  k_proj_out<<<dim3(64, 4), 256, 0, stream>>>(aws, wfc, out);
}